// Round 1
// baseline (459.946 us; speedup 1.0000x reference)
//
#include <hip/hip_runtime.h>
#include <math.h>

// Problem constants (fixed by setup_inputs)
#define B_  32
#define N_  1024
#define D_  64
#define H_  8
#define K_  128
#define HK_ 1024
#define T_  12

// ---------------------------------------------------------------------------
// K1: x[b,n,d] = mean_t node_set[b,d,n,t]; also inv_xn[b,n] = 1/||x[b,n,:]||
// and tempsum[b,d] += sum_n x[b,n,d] (atomic, zeroed by memset before launch).
// Block: 256 thr, handles (b, 64-n tile). LDS transpose for coalesced x write.
// ---------------------------------------------------------------------------
__global__ __launch_bounds__(256) void k1_mean(const float* __restrict__ ns,
        float* __restrict__ x, float* __restrict__ invxn,
        float* __restrict__ tempsum) {
    __shared__ float tile[64][65];          // [n_local][d], pad->conflict-free
    int b    = blockIdx.x >> 4;
    int n0   = (blockIdx.x & 15) << 6;
    int lane = threadIdx.x & 63;
    int w    = threadIdx.x >> 6;
    // phase 1: lane = n (coalesced-in-aggregate 48B/lane reads), wave covers d
    #pragma unroll
    for (int j = 0; j < 16; ++j) {
        int d = w * 16 + j;
        const float4* p = (const float4*)(ns +
            ((size_t)((b * 64 + d) * 1024 + n0 + lane)) * 12);   // 48B aligned
        float4 a = p[0], c = p[1], e = p[2];
        float s = ((a.x + a.y) + (a.z + a.w)) + ((c.x + c.y) + (c.z + c.w))
                + ((e.x + e.y) + (e.z + e.w));
        tile[lane][d] = s * (1.0f / 12.0f);
    }
    __syncthreads();
    // phase 2a: write x with lane = d (coalesced 256B/wave)
    #pragma unroll
    for (int j = 0; j < 16; ++j) {
        int r = w * 16 + j;
        x[((size_t)(b * 1024 + n0 + r)) * 64 + lane] = tile[r][lane];
    }
    // phase 2b: row norms -> inv_xn
    #pragma unroll
    for (int j = 0; j < 16; ++j) {
        int r = w * 16 + j;
        float v  = tile[r][lane];
        float ss = v * v;
        #pragma unroll
        for (int o = 32; o; o >>= 1) ss += __shfl_xor(ss, o);
        if (lane == 0) invxn[b * 1024 + n0 + r] = 1.0f / sqrtf(fmaxf(ss, 1e-30f));
    }
    // phase 2c: column sums over n for temp (one wave)
    if (threadIdx.x < 64) {
        float s = 0.0f;
        #pragma unroll 8
        for (int r = 0; r < 64; ++r) s += tile[r][threadIdx.x];
        atomicAdd(&tempsum[b * 64 + threadIdx.x], s);
    }
}

// ---------------------------------------------------------------------------
// K2: h_avg[b,e] = tanh(sum_d (tempsum[b,d]/N) * W0[d,e]).  grid=B, block=64
// ---------------------------------------------------------------------------
__global__ void k2_havg(const float* __restrict__ tempsum,
        const float* __restrict__ W0, float* __restrict__ h_avg) {
    __shared__ float t[64];
    int b = blockIdx.x, e = threadIdx.x;
    t[e] = tempsum[b * 64 + e] * (1.0f / 1024.0f);
    __syncthreads();
    float a = 0.0f;
    #pragma unroll 8
    for (int d = 0; d < 64; ++d) a += t[d] * W0[d * 64 + e];
    h_avg[b * 64 + e] = tanhf(a);
}

// ---------------------------------------------------------------------------
// K3: att[b,n] = x[b,n,:]·h_avg[b,:];  cent[b,d] += sum_n att*x  (atomic).
// grid = B*8 (128-n slices), block = 256 (4 waves, lane = d).
// ---------------------------------------------------------------------------
__global__ __launch_bounds__(256) void k3_cent(const float* __restrict__ x,
        const float* __restrict__ h_avg, float* __restrict__ cent) {
    __shared__ float ha[64];
    __shared__ float cp[4][64];
    int b    = blockIdx.x >> 3;
    int n0   = (blockIdx.x & 7) << 7;
    int lane = threadIdx.x & 63;
    int w    = threadIdx.x >> 6;
    if (threadIdx.x < 64) ha[threadIdx.x] = h_avg[b * 64 + threadIdx.x];
    __syncthreads();
    float hv = ha[lane];
    float cw = 0.0f;
    for (int nn = w; nn < 128; nn += 4) {
        float xv = x[((size_t)(b * 1024 + n0 + nn)) * 64 + lane];
        float d  = xv * hv;
        #pragma unroll
        for (int o = 32; o; o >>= 1) d += __shfl_xor(d, o);   // att broadcast
        cw += d * xv;
    }
    cp[w][lane] = cw;
    __syncthreads();
    if (w == 0)
        atomicAdd(&cent[b * 64 + lane],
                  cp[0][lane] + cp[1][lane] + cp[2][lane] + cp[3][lane]);
}

// ---------------------------------------------------------------------------
// K4: centroid MLP. bc[b,hk,d] = relu(sum_h relu(cent[b,d]*w_i2c[h]+b_i2c[h])
//      * W_lin[hk,h] + b_lin[hk]);  inv_cn[b,hk] = cn>0 ? 1/||bc|| : 0.
// One wave per (b,hk): lane = d.  grid = B*HK/4, block = 256.
// ---------------------------------------------------------------------------
__global__ __launch_bounds__(256) void k4_bc(const float* __restrict__ cent,
        const float* __restrict__ w_i2c, const float* __restrict__ b_i2c,
        const float* __restrict__ W_lin, const float* __restrict__ b_lin,
        float* __restrict__ bc, float* __restrict__ invcn) {
    int lane = threadIdx.x & 63;
    int w    = threadIdx.x >> 6;
    int g    = blockIdx.x * 4 + w;          // b*1024 + hk
    int b    = g >> 10, kk = g & 1023;
    float c   = cent[b * 64 + lane];
    float pre = b_lin[kk];
    #pragma unroll
    for (int h = 0; h < 8; ++h) {
        float b1 = fmaxf(c * w_i2c[h] + b_i2c[h], 0.0f);
        pre += b1 * W_lin[kk * 8 + h];
    }
    float v = fmaxf(pre, 0.0f);
    bc[((size_t)g) * 64 + lane] = v;
    float ss = v * v;
    #pragma unroll
    for (int o = 32; o; o >>= 1) ss += __shfl_xor(ss, o);
    if (lane == 0) invcn[g] = (ss > 0.0f) ? (1.0f / sqrtf(ss)) : 0.0f;
}

// ---------------------------------------------------------------------------
// K5 (dominant): per (b, 128-n tile), for each h: dots GEMM [128k x 64d]x[64d
// x 128n] via 8x8 register tiles from LDS, fold inv_cn*inv_xn, cross-thread
// sum over k -> 1/(s+1e-10), accumulate conv_w[h]*chead*sinv into Cacc.
// C[b,k,n] = Cacc + conv_b.  grid = B*8 = 256 blocks, block = 256.
// ---------------------------------------------------------------------------
__global__ __launch_bounds__(256, 1) void k5_assign(const float* __restrict__ x,
        const float* __restrict__ bc, const float* __restrict__ invxn,
        const float* __restrict__ invcn, const float* __restrict__ conv_w,
        const float* __restrict__ conv_b, float* __restrict__ C) {
    __shared__ float xt[128][68];    // [n][d] padded (stride%32==4 w/ float4)
    __shared__ float bct[128][68];   // [k][d]
    __shared__ float invx_s[128];
    __shared__ float invc_s[128];
    __shared__ float sred[16][132];  // [q][n] k-partial sums, padded
    __shared__ float sinv[128];
    int b   = blockIdx.x >> 3;
    int n0  = (blockIdx.x & 7) << 7;
    int tid = threadIdx.x;
    {   // stage x tile (coalesced float4)
        int r = tid >> 1, dh = (tid & 1) << 5;
        const float4* src = (const float4*)(x + ((size_t)(b * 1024 + n0 + r)) * 64 + dh);
        float4* dst = (float4*)(&xt[r][dh]);
        #pragma unroll
        for (int qq = 0; qq < 8; ++qq) dst[qq] = src[qq];
    }
    if (tid < 128) invx_s[tid] = invxn[b * 1024 + n0 + tid];
    float Cacc[8][8];
    #pragma unroll
    for (int i = 0; i < 8; ++i)
        #pragma unroll
        for (int j = 0; j < 8; ++j) Cacc[i][j] = 0.0f;
    int q = tid >> 4, p = tid & 15;          // k-base, n-base (stride-16 tiles)
    float cb = conv_b[0];
    for (int h = 0; h < 8; ++h) {
        {   // stage bc tile for this head
            int r = tid >> 1, dh = (tid & 1) << 5;
            const float4* src = (const float4*)(bc + ((size_t)(b * 1024 + h * 128 + r)) * 64 + dh);
            float4* dst = (float4*)(&bct[r][dh]);
            #pragma unroll
            for (int qq = 0; qq < 8; ++qq) dst[qq] = src[qq];
        }
        if (tid < 128) invc_s[tid] = invcn[b * 1024 + h * 128 + tid];
        __syncthreads();
        float acc[8][8];
        #pragma unroll
        for (int i = 0; i < 8; ++i)
            #pragma unroll
            for (int j = 0; j < 8; ++j) acc[i][j] = 0.0f;
        for (int dc = 0; dc < 64; dc += 4) {
            float4 bv[8], xv[8];
            #pragma unroll
            for (int i = 0; i < 8; ++i) bv[i] = *(const float4*)(&bct[q + 16 * i][dc]);
            #pragma unroll
            for (int j = 0; j < 8; ++j) xv[j] = *(const float4*)(&xt[p + 16 * j][dc]);
            #pragma unroll
            for (int i = 0; i < 8; ++i)
                #pragma unroll
                for (int j = 0; j < 8; ++j)
                    acc[i][j] += bv[i].x * xv[j].x + bv[i].y * xv[j].y
                               + bv[i].z * xv[j].z + bv[i].w * xv[j].w;
        }
        // fold cosine denominators in-place; per-thread k-partials of s
        float part[8];
        #pragma unroll
        for (int j = 0; j < 8; ++j) part[j] = 0.0f;
        #pragma unroll
        for (int i = 0; i < 8; ++i) {
            float ic = invc_s[q + 16 * i];
            #pragma unroll
            for (int j = 0; j < 8; ++j) {
                float v = acc[i][j] * ic * invx_s[p + 16 * j];
                acc[i][j] = v;
                part[j] += v;
            }
        }
        #pragma unroll
        for (int j = 0; j < 8; ++j) sred[q][p + 16 * j] = part[j];
        __syncthreads();
        if (tid < 128) {
            float s = 0.0f;
            #pragma unroll
            for (int qq = 0; qq < 16; ++qq) s += sred[qq][tid];
            sinv[tid] = 1.0f / (s + 1e-10f);
        }
        __syncthreads();
        float cwv = conv_w[h];
        #pragma unroll
        for (int j = 0; j < 8; ++j) {
            float si = sinv[p + 16 * j];
            #pragma unroll
            for (int i = 0; i < 8; ++i) Cacc[i][j] += cwv * acc[i][j] * si;
        }
        __syncthreads();   // sinv/sred safe before next head overwrites
    }
    #pragma unroll
    for (int i = 0; i < 8; ++i) {
        int k = q + 16 * i;
        #pragma unroll
        for (int j = 0; j < 8; ++j)
            C[((size_t)(b * 128 + k)) * 1024 + n0 + p + 16 * j] = Cacc[i][j] + cb;
    }
}

// ---------------------------------------------------------------------------
// K6: nns[b,k,d] = sum_n C[b,k,n]*x[b,n,d]; out = nns@W_feat^T + b_feat.
// grid = B*8 (16 k rows each), block = 256 (4 waves, lane = d then lane = o).
// C loads are wave-uniform (s_load), x rows coalesced.
// ---------------------------------------------------------------------------
__global__ __launch_bounds__(256) void k6_out(const float* __restrict__ C,
        const float* __restrict__ x, const float* __restrict__ W_feat,
        const float* __restrict__ b_feat, float* __restrict__ out) {
    __shared__ float wf[64][65];
    __shared__ float nns[16][65];
    int b    = blockIdx.x >> 3;
    int k0   = (blockIdx.x & 7) << 4;
    int lane = threadIdx.x & 63;
    int w    = threadIdx.x >> 6;
    for (int t = threadIdx.x; t < 4096; t += 256) wf[t >> 6][t & 63] = W_feat[t];
    float acc0 = 0, acc1 = 0, acc2 = 0, acc3 = 0;
    const float* xb = x + ((size_t)b << 16);
    const float* Cb = C + (((size_t)(b * 128 + k0 + w * 4)) << 10);
    #pragma unroll 4
    for (int n = 0; n < 1024; ++n) {
        float xv = xb[n * 64 + lane];
        acc0 += Cb[n]        * xv;
        acc1 += Cb[1024 + n] * xv;
        acc2 += Cb[2048 + n] * xv;
        acc3 += Cb[3072 + n] * xv;
    }
    nns[w * 4 + 0][lane] = acc0;
    nns[w * 4 + 1][lane] = acc1;
    nns[w * 4 + 2][lane] = acc2;
    nns[w * 4 + 3][lane] = acc3;
    __syncthreads();
    float bf = b_feat[lane];
    #pragma unroll
    for (int m = 0; m < 4; ++m) {
        float a = bf;
        #pragma unroll 8
        for (int d = 0; d < 64; ++d) a += nns[w * 4 + m][d] * wf[lane][d];
        out[((size_t)(b * 128 + k0 + w * 4 + m)) * 64 + lane] = a;
    }
}

// ---------------------------------------------------------------------------
extern "C" void kernel_launch(void* const* d_in, const int* in_sizes, int n_in,
                              void* d_out, int out_size, void* d_ws, size_t ws_size,
                              hipStream_t stream) {
    const float* node_set = (const float*)d_in[0];
    // d_in[1] = adj : UNUSED by the reference
    const float* W0     = (const float*)d_in[2];
    const float* w_i2c  = (const float*)d_in[3];
    const float* b_i2c  = (const float*)d_in[4];
    const float* W_lin  = (const float*)d_in[5];
    const float* b_lin  = (const float*)d_in[6];
    const float* conv_w = (const float*)d_in[7];
    const float* conv_b = (const float*)d_in[8];
    const float* W_feat = (const float*)d_in[9];
    const float* b_feat = (const float*)d_in[10];
    float* out = (float*)d_out;
    float* ws  = (float*)d_ws;

    // workspace layout (floats)
    float* x       = ws;                    // 2,097,152  [B,N,D]
    float* invxn   = ws + 2097152;          //    32,768  [B,N]
    float* tempsum = ws + 2129920;          //     2,048  [B,D]   (memset 0)
    float* cent    = ws + 2131968;          //     2,048  [B,D]   (memset 0)
    float* h_avg   = ws + 2134016;          //     2,048  [B,D]
    float* bc      = ws + 2136064;          // 2,097,152  [B,HK,D]
    float* invcn   = ws + 4233216;          //    32,768  [B,HK]
    float* Cmat    = ws + 4265984;          // 4,194,304  [B,K,N]  (~33.8MB end)

    hipMemsetAsync(tempsum, 0, 4096 * sizeof(float), stream);  // tempsum+cent

    k1_mean <<<B_ * 16, 256, 0, stream>>>(node_set, x, invxn, tempsum);
    k2_havg <<<B_, 64, 0, stream>>>(tempsum, W0, h_avg);
    k3_cent <<<B_ * 8, 256, 0, stream>>>(x, h_avg, cent);
    k4_bc   <<<B_ * HK_ / 4, 256, 0, stream>>>(cent, w_i2c, b_i2c, W_lin, b_lin, bc, invcn);
    k5_assign<<<B_ * 8, 256, 0, stream>>>(x, bc, invxn, invcn, conv_w, conv_b, Cmat);
    k6_out  <<<B_ * 8, 256, 0, stream>>>(Cmat, x, W_feat, b_feat, out);
}

// Round 2
// 379.420 us; speedup vs baseline: 1.2122x; 1.2122x over previous
//
#include <hip/hip_runtime.h>
#include <math.h>

// Problem constants (fixed by setup_inputs)
#define B_  32
#define N_  1024
#define D_  64
#define H_  8
#define K_  128
#define HK_ 1024

// ---------------------------------------------------------------------------
// K1: x[b,n,d] = mean_t node_set[b,d,n,t]; inv_xn[b,n] = 1/||x[b,n,:]||;
// tempsum[b,d] += sum_n x[b,n,d] (atomic; zeroed by memset).
// 512 threads (8 waves), grid B*16 -> 2 blocks/CU, 16 waves/CU (BW-bound).
// ---------------------------------------------------------------------------
__global__ __launch_bounds__(512) void k1_mean(const float* __restrict__ ns,
        float* __restrict__ x, float* __restrict__ invxn,
        float* __restrict__ tempsum) {
    __shared__ float tile[64][65];          // [n_local][d], pad -> conflict-free
    int b    = blockIdx.x >> 4;
    int n0   = (blockIdx.x & 15) << 6;
    int lane = threadIdx.x & 63;
    int w    = threadIdx.x >> 6;            // 0..7
    // phase 1: lane = n (48B/lane contiguous reads), 8 waves cover d
    #pragma unroll
    for (int j = 0; j < 8; ++j) {
        int d = w * 8 + j;
        const float4* p = (const float4*)(ns +
            ((size_t)((b * 64 + d) * 1024 + n0 + lane)) * 12);   // 48B aligned
        float4 a = p[0], c = p[1], e = p[2];
        float s = ((a.x + a.y) + (a.z + a.w)) + ((c.x + c.y) + (c.z + c.w))
                + ((e.x + e.y) + (e.z + e.w));
        tile[lane][d] = s * (1.0f / 12.0f);
    }
    __syncthreads();
    // phase 2: write x (lane = d, coalesced) + row norms
    #pragma unroll
    for (int j = 0; j < 8; ++j) {
        int r = w * 8 + j;
        float v = tile[r][lane];
        x[((size_t)(b * 1024 + n0 + r)) * 64 + lane] = v;
        float ss = v * v;
        #pragma unroll
        for (int o = 32; o; o >>= 1) ss += __shfl_xor(ss, o);
        if (lane == 0) invxn[b * 1024 + n0 + r] = 1.0f / sqrtf(fmaxf(ss, 1e-30f));
    }
    // column sums over n for temp (one wave)
    if (threadIdx.x < 64) {
        float s = 0.0f;
        #pragma unroll 16
        for (int r = 0; r < 64; ++r) s += tile[r][threadIdx.x];
        atomicAdd(&tempsum[b * 64 + threadIdx.x], s);
    }
}

// ---------------------------------------------------------------------------
// K3 (k2 fused): per block compute h_avg[b,:]=tanh((tempsum/N)@W0) redundantly,
// then att[n]=x[n,:]·h_avg, cent[b,d] += sum_n att*x[n,d] (atomic).
// grid = B*16 (64-n slices), block 256 (4 waves, lane = d).
// ---------------------------------------------------------------------------
__global__ __launch_bounds__(256) void k3_cent(const float* __restrict__ x,
        const float* __restrict__ tempsum, const float* __restrict__ W0,
        float* __restrict__ cent) {
    __shared__ float t[64];
    __shared__ float ha[64];
    __shared__ float cp[4][64];
    int b    = blockIdx.x >> 4;
    int n0   = (blockIdx.x & 15) << 6;
    int lane = threadIdx.x & 63;
    int w    = threadIdx.x >> 6;
    if (threadIdx.x < 64) t[threadIdx.x] = tempsum[b * 64 + threadIdx.x] * (1.0f / 1024.0f);
    __syncthreads();
    if (threadIdx.x < 64) {                  // h_avg: 64x64 matvec, coalesced W0 rows
        float a = 0.0f;
        #pragma unroll 8
        for (int d = 0; d < 64; ++d) a += t[d] * W0[d * 64 + threadIdx.x];
        ha[threadIdx.x] = tanhf(a);
    }
    __syncthreads();
    float hv = ha[lane];
    float cw = 0.0f;
    for (int nn = w; nn < 64; nn += 4) {
        float xv = x[((size_t)(b * 1024 + n0 + nn)) * 64 + lane];
        float d  = xv * hv;
        #pragma unroll
        for (int o = 32; o; o >>= 1) d += __shfl_xor(d, o);   // att broadcast
        cw += d * xv;
    }
    cp[w][lane] = cw;
    __syncthreads();
    if (w == 0)
        atomicAdd(&cent[b * 64 + lane],
                  cp[0][lane] + cp[1][lane] + cp[2][lane] + cp[3][lane]);
}

// ---------------------------------------------------------------------------
// K4: centroid MLP. One wave handles 4 consecutive hk (cent loaded once).
// grid = B*HK/16 = 2048 blocks, block 256 (4 waves).
// ---------------------------------------------------------------------------
__global__ __launch_bounds__(256) void k4_bc(const float* __restrict__ cent,
        const float* __restrict__ w_i2c, const float* __restrict__ b_i2c,
        const float* __restrict__ W_lin, const float* __restrict__ b_lin,
        float* __restrict__ bc, float* __restrict__ invcn) {
    int lane = threadIdx.x & 63;
    int w    = threadIdx.x >> 6;
    int gg   = blockIdx.x * 4 + w;          // wave id, 4 hk each
    int b    = gg >> 8;
    int kk0  = (gg & 255) * 4;
    float c = cent[b * 64 + lane];
    float b1[8];
    #pragma unroll
    for (int h = 0; h < 8; ++h) b1[h] = fmaxf(c * w_i2c[h] + b_i2c[h], 0.0f);
    #pragma unroll
    for (int u = 0; u < 4; ++u) {
        int kk = kk0 + u;
        float pre = b_lin[kk];
        #pragma unroll
        for (int h = 0; h < 8; ++h) pre += b1[h] * W_lin[kk * 8 + h];
        float v = fmaxf(pre, 0.0f);
        bc[((size_t)(b * 1024 + kk)) * 64 + lane] = v;
        float ss = v * v;
        #pragma unroll
        for (int o = 32; o; o >>= 1) ss += __shfl_xor(ss, o);
        if (lane == 0) invcn[b * 1024 + kk] = (ss > 0.0f) ? (1.0f / sqrtf(ss)) : 0.0f;
    }
}

// ---------------------------------------------------------------------------
// K5 (dominant): per (b, 64-n tile), for each h: dots GEMM [128k x 64d] x
// [64d x 64n] via 8x4 register tiles from LDS, fold inv_cn*inv_xn, k-sum ->
// 1/(s+1e-10), accumulate conv_w[h]*chead*sinv. grid = B*16 = 512 blocks,
// block 256 -> 2 blocks/CU (57.6KB LDS), 8 waves/CU.
// ---------------------------------------------------------------------------
__global__ __launch_bounds__(256, 2) void k5_assign(const float* __restrict__ x,
        const float* __restrict__ bc, const float* __restrict__ invxn,
        const float* __restrict__ invcn, const float* __restrict__ conv_w,
        const float* __restrict__ conv_b, float* __restrict__ C) {
    __shared__ float xt[64][68];     // [n][d] padded
    __shared__ float bct[128][68];   // [k][d]
    __shared__ float invx_s[64];
    __shared__ float invc_s[128];
    __shared__ float sred[16][68];   // [q][n] k-partial sums
    __shared__ float sinv[64];
    int b   = blockIdx.x >> 4;
    int n0  = (blockIdx.x & 15) << 6;
    int tid = threadIdx.x;
    {   // stage x tile: 64 rows x 64 d, 16 floats/thread
        int r = tid >> 2, dh = (tid & 3) << 4;
        const float4* src = (const float4*)(x + ((size_t)(b * 1024 + n0 + r)) * 64 + dh);
        float4* dst = (float4*)(&xt[r][dh]);
        dst[0] = src[0]; dst[1] = src[1]; dst[2] = src[2]; dst[3] = src[3];
    }
    if (tid < 64) invx_s[tid] = invxn[b * 1024 + n0 + tid];
    float Cacc[8][4];
    #pragma unroll
    for (int i = 0; i < 8; ++i)
        #pragma unroll
        for (int j = 0; j < 4; ++j) Cacc[i][j] = 0.0f;
    int q = tid >> 4, p = tid & 15;          // k-slot (16), n-slot (16)
    float cb = conv_b[0];
    for (int h = 0; h < 8; ++h) {
        {   // stage bc tile for this head: 128 rows
            int r = tid >> 1, dh = (tid & 1) << 5;
            const float4* src = (const float4*)(bc + ((size_t)(b * 1024 + h * 128 + r)) * 64 + dh);
            float4* dst = (float4*)(&bct[r][dh]);
            #pragma unroll
            for (int u = 0; u < 8; ++u) dst[u] = src[u];
        }
        if (tid < 128) invc_s[tid] = invcn[b * 1024 + h * 128 + tid];
        __syncthreads();
        float acc[8][4];
        #pragma unroll
        for (int i = 0; i < 8; ++i)
            #pragma unroll
            for (int j = 0; j < 4; ++j) acc[i][j] = 0.0f;
        for (int dc = 0; dc < 64; dc += 4) {
            float4 bv[8], xv[4];
            #pragma unroll
            for (int i = 0; i < 8; ++i) bv[i] = *(const float4*)(&bct[q + 16 * i][dc]);
            #pragma unroll
            for (int j = 0; j < 4; ++j) xv[j] = *(const float4*)(&xt[p + 16 * j][dc]);
            #pragma unroll
            for (int i = 0; i < 8; ++i)
                #pragma unroll
                for (int j = 0; j < 4; ++j)
                    acc[i][j] += bv[i].x * xv[j].x + bv[i].y * xv[j].y
                               + bv[i].z * xv[j].z + bv[i].w * xv[j].w;
        }
        // fold cosine denominators; per-thread k-partials of the normalizer
        float part[4];
        #pragma unroll
        for (int j = 0; j < 4; ++j) part[j] = 0.0f;
        #pragma unroll
        for (int i = 0; i < 8; ++i) {
            float ic = invc_s[q + 16 * i];
            #pragma unroll
            for (int j = 0; j < 4; ++j) {
                float v = acc[i][j] * ic * invx_s[p + 16 * j];
                acc[i][j] = v;
                part[j] += v;
            }
        }
        #pragma unroll
        for (int j = 0; j < 4; ++j) sred[q][p + 16 * j] = part[j];
        __syncthreads();
        if (tid < 64) {
            float s = 0.0f;
            #pragma unroll
            for (int qq = 0; qq < 16; ++qq) s += sred[qq][tid];
            sinv[tid] = 1.0f / (s + 1e-10f);
        }
        __syncthreads();
        float cwv = conv_w[h];
        #pragma unroll
        for (int j = 0; j < 4; ++j) {
            float si = sinv[p + 16 * j];
            #pragma unroll
            for (int i = 0; i < 8; ++i) Cacc[i][j] += cwv * acc[i][j] * si;
        }
        __syncthreads();   // protect bct/sred before next head overwrites
    }
    #pragma unroll
    for (int i = 0; i < 8; ++i) {
        int k = q + 16 * i;
        #pragma unroll
        for (int j = 0; j < 4; ++j)
            C[((size_t)(b * 128 + k)) * 1024 + n0 + p + 16 * j] = Cacc[i][j] + cb;
    }
}

// ---------------------------------------------------------------------------
// K6: LDS-tiled GEMM nns[k,d] = sum_n C[b,k,n]*x[b,n,d] over n-chunks of 128,
// then fused projection out = nns@W_feat^T + b_feat.
// grid = B*8 (16 k rows each), block 256, 65KB LDS -> 2 blocks/CU.
// ---------------------------------------------------------------------------
__global__ __launch_bounds__(256, 2) void k6_out(const float* __restrict__ C,
        const float* __restrict__ x, const float* __restrict__ Wf,
        const float* __restrict__ bfeat, float* __restrict__ out) {
    __shared__ float xt[128][68];
    __shared__ float ct[16][132];
    __shared__ float nnst[16][68];
    __shared__ float wfs[64][68];
    int b   = blockIdx.x >> 3;
    int k0  = (blockIdx.x & 7) << 4;
    int tid = threadIdx.x;
    int kq  = tid >> 4, p = tid & 15;        // k row (16), d quad (16)
    for (int t = tid; t < 4096; t += 256) wfs[t >> 6][t & 63] = Wf[t];
    float acc[4] = {0.0f, 0.0f, 0.0f, 0.0f};
    for (int c = 0; c < 8; ++c) {
        __syncthreads();                      // protect prev chunk reads
        {   // stage x chunk [128n x 64d]
            int r = tid >> 1, dh = (tid & 1) << 5;
            const float4* src = (const float4*)(x + ((size_t)(b * 1024 + c * 128 + r)) * 64 + dh);
            float4* dst = (float4*)(&xt[r][dh]);
            #pragma unroll
            for (int u = 0; u < 8; ++u) dst[u] = src[u];
        }
        for (int t = tid; t < 2048; t += 256)  // stage C chunk [16k x 128n]
            ct[t >> 7][t & 127] = C[((size_t)(b * 128 + k0 + (t >> 7))) * 1024 + c * 128 + (t & 127)];
        __syncthreads();
        #pragma unroll 8
        for (int n = 0; n < 128; ++n) {
            float  cv = ct[kq][n];
            float4 xv = *(const float4*)(&xt[n][p << 2]);
            acc[0] += cv * xv.x; acc[1] += cv * xv.y;
            acc[2] += cv * xv.z; acc[3] += cv * xv.w;
        }
    }
    __syncthreads();
    nnst[kq][(p << 2) + 0] = acc[0];
    nnst[kq][(p << 2) + 1] = acc[1];
    nnst[kq][(p << 2) + 2] = acc[2];
    nnst[kq][(p << 2) + 3] = acc[3];
    __syncthreads();
    // projection: thread owns (kq, o = 4p..4p+3)
    float o0 = bfeat[(p << 2) + 0], o1 = bfeat[(p << 2) + 1];
    float o2 = bfeat[(p << 2) + 2], o3 = bfeat[(p << 2) + 3];
    #pragma unroll
    for (int dc = 0; dc < 64; dc += 4) {
        float4 nv = *(const float4*)(&nnst[kq][dc]);
        float4 w0 = *(const float4*)(&wfs[(p << 2) + 0][dc]);
        float4 w1 = *(const float4*)(&wfs[(p << 2) + 1][dc]);
        float4 w2 = *(const float4*)(&wfs[(p << 2) + 2][dc]);
        float4 w3 = *(const float4*)(&wfs[(p << 2) + 3][dc]);
        o0 += nv.x * w0.x + nv.y * w0.y + nv.z * w0.z + nv.w * w0.w;
        o1 += nv.x * w1.x + nv.y * w1.y + nv.z * w1.z + nv.w * w1.w;
        o2 += nv.x * w2.x + nv.y * w2.y + nv.z * w2.z + nv.w * w2.w;
        o3 += nv.x * w3.x + nv.y * w3.y + nv.z * w3.z + nv.w * w3.w;
    }
    float4 ov = make_float4(o0, o1, o2, o3);
    *(float4*)(out + ((size_t)(b * 128 + k0 + kq)) * 64 + (p << 2)) = ov;
}

// ---------------------------------------------------------------------------
extern "C" void kernel_launch(void* const* d_in, const int* in_sizes, int n_in,
                              void* d_out, int out_size, void* d_ws, size_t ws_size,
                              hipStream_t stream) {
    const float* node_set = (const float*)d_in[0];
    // d_in[1] = adj : UNUSED by the reference
    const float* W0     = (const float*)d_in[2];
    const float* w_i2c  = (const float*)d_in[3];
    const float* b_i2c  = (const float*)d_in[4];
    const float* W_lin  = (const float*)d_in[5];
    const float* b_lin  = (const float*)d_in[6];
    const float* conv_w = (const float*)d_in[7];
    const float* conv_b = (const float*)d_in[8];
    const float* W_feat = (const float*)d_in[9];
    const float* b_feat = (const float*)d_in[10];
    float* out = (float*)d_out;
    float* ws  = (float*)d_ws;

    // workspace layout (floats)
    float* x       = ws;                    // 2,097,152  [B,N,D]
    float* invxn   = ws + 2097152;          //    32,768  [B,N]
    float* tempsum = ws + 2129920;          //     2,048  [B,D]   (memset 0)
    float* cent    = ws + 2131968;          //     2,048  [B,D]   (memset 0)
    float* bc      = ws + 2134016;          // 2,097,152  [B,HK,D]
    float* invcn   = ws + 4231168;          //    32,768  [B,HK]
    float* Cmat    = ws + 4263936;          // 4,194,304  [B,K,N]

    hipMemsetAsync(tempsum, 0, 4096 * sizeof(float), stream);  // tempsum+cent

    k1_mean  <<<B_ * 16, 512, 0, stream>>>(node_set, x, invxn, tempsum);
    k3_cent  <<<B_ * 16, 256, 0, stream>>>(x, tempsum, W0, cent);
    k4_bc    <<<2048,    256, 0, stream>>>(cent, w_i2c, b_i2c, W_lin, b_lin, bc, invcn);
    k5_assign<<<B_ * 16, 256, 0, stream>>>(x, bc, invxn, invcn, conv_w, conv_b, Cmat);
    k6_out   <<<B_ * 8,  256, 0, stream>>>(Cmat, x, W_feat, b_feat, out);
}